// Round 2
// baseline (82.303 us; speedup 1.0000x reference)
//
#include <hip/hip_runtime.h>

#define N 4096
#define IN_F 256
#define OUT_F 64
#define HEADS 4
#define ALPHA 0.2f
#define RPW 8     // rows per wave in the h-GEMM
#define MAXD 128  // max degree per row (mean ~21, 128 is >20 sigma)

// ---------------------------------------------------------------------------
// K1: build hamilton[4][256][64] from W_heads[4][64][64]
// ---------------------------------------------------------------------------
__global__ __launch_bounds__(256) void k_build_ham(const float* __restrict__ W,
                                                   float* __restrict__ ham) {
    int tid = blockIdx.x * 256 + threadIdx.x;          // 0..65535
    int hd = tid >> 14;
    int kk = (tid >> 6) & 255;
    int f  = tid & 63;
    int q = kk >> 6, kr = kk & 63;
    int p = f >> 4,  fr = f & 15;
    const int   comp_t[4][4] = {{0,1,2,3},{1,0,3,2},{2,3,0,1},{3,2,1,0}};
    const float sign_t[4][4] = {{1.f,-1.f,-1.f,-1.f},
                                {1.f, 1.f,-1.f, 1.f},
                                {1.f, 1.f, 1.f,-1.f},
                                {1.f,-1.f, 1.f, 1.f}};
    int   c = comp_t[q][p];
    float s = sign_t[q][p];
    ham[tid] = s * W[(hd * 64 + kr) * 64 + c * 16 + fr];
}

// ---------------------------------------------------------------------------
// K2: h[i][hd*64+f] = sum_k x[i][k] * ham[hd][k][f]   (fp32, vector ALU)
// One head per block; hamilton head (64 KB) staged in LDS. 4 waves x RPW rows.
// lane == feature. x loads are wave-uniform -> scalar pipe.
// Fused: e_src/e_dst dot products via shuffle reduce.
// ---------------------------------------------------------------------------
__global__ __launch_bounds__(256) void k_hgemm(const float* __restrict__ x,
                                               const float* __restrict__ ham,
                                               const float* __restrict__ a,
                                               float* __restrict__ h,
                                               float* __restrict__ e_src_p,
                                               float* __restrict__ e_dst_p) {
    __shared__ float lham[IN_F * OUT_F];   // 64 KB
    const int hd   = blockIdx.y;
    const int wave = threadIdx.x >> 6;
    const int lane = threadIdx.x & 63;

    // stage this head's hamilton into LDS (contiguous float4 copy)
    {
        const float4* src = reinterpret_cast<const float4*>(ham + hd * (IN_F * OUT_F));
        float4* dst = reinterpret_cast<float4*>(lham);
        for (int t = threadIdx.x; t < IN_F * OUT_F / 4; t += 256) dst[t] = src[t];
    }
    __syncthreads();

    const int i0 = (blockIdx.x * 4 + wave) * RPW;

    float acc[RPW];
#pragma unroll
    for (int r = 0; r < RPW; ++r) acc[r] = 0.f;

#pragma unroll 2
    for (int k = 0; k < IN_F; k += 4) {
        const float hv0 = lham[(k + 0) * OUT_F + lane];
        const float hv1 = lham[(k + 1) * OUT_F + lane];
        const float hv2 = lham[(k + 2) * OUT_F + lane];
        const float hv3 = lham[(k + 3) * OUT_F + lane];
#pragma unroll
        for (int r = 0; r < RPW; ++r) {
            const float4 xv = *reinterpret_cast<const float4*>(&x[(i0 + r) * IN_F + k]);
            acc[r] = fmaf(xv.x, hv0, acc[r]);
            acc[r] = fmaf(xv.y, hv1, acc[r]);
            acc[r] = fmaf(xv.z, hv2, acc[r]);
            acc[r] = fmaf(xv.w, hv3, acc[r]);
        }
    }

    const float a_s = a[hd * 128 + lane];
    const float a_d = a[hd * 128 + 64 + lane];
#pragma unroll
    for (int r = 0; r < RPW; ++r) {
        h[(i0 + r) * 256 + hd * 64 + lane] = acc[r];   // [N][HEADS*64] layout
        float p = acc[r] * a_s;
        float q = acc[r] * a_d;
#pragma unroll
        for (int off = 32; off > 0; off >>= 1) {
            p += __shfl_xor(p, off);
            q += __shfl_xor(q, off);
        }
        if (lane == 0) {
            e_src_p[(i0 + r) * 4 + hd] = p;
            e_dst_p[(i0 + r) * 4 + hd] = q;
        }
    }
}

// ---------------------------------------------------------------------------
// K3: Dmax[hd] = max_j e_dst[hd][j]  (upper bound for shift-stable softmax)
// ---------------------------------------------------------------------------
__global__ __launch_bounds__(256) void k_dmax(const float* __restrict__ e_dst_p,
                                              float* __restrict__ Dmax) {
    __shared__ float sm[256];
    const int hd = blockIdx.x;
    float m = -3.0e38f;
    for (int j = threadIdx.x; j < N; j += 256)
        m = fmaxf(m, e_dst_p[j * 4 + hd]);
    sm[threadIdx.x] = m;
    __syncthreads();
    for (int s = 128; s > 0; s >>= 1) {
        if (threadIdx.x < s) sm[threadIdx.x] = fmaxf(sm[threadIdx.x], sm[threadIdx.x + s]);
        __syncthreads();
    }
    if (threadIdx.x == 0) Dmax[hd] = sm[0];
}

// ---------------------------------------------------------------------------
// K4: CSR build — pure streaming scan of adj, one wave per row.
// Prefetch-1-deep float4 scan; ballot+popcount compaction (deterministic order).
// ---------------------------------------------------------------------------
__global__ __launch_bounds__(256) void k_csr(const float* __restrict__ adj,
                                             int* __restrict__ cnt,
                                             int* __restrict__ idx) {
    const int wave = threadIdx.x >> 6;
    const int lane = threadIdx.x & 63;
    const int i = blockIdx.x * 4 + wave;

    const float4* arow = reinterpret_cast<const float4*>(adj + (size_t)i * N);
    int* rowidx = idx + i * MAXD;
    int base = 0;

    float4 av = arow[lane];            // prefetch t=0
    for (int t = 0; t < N / 256; ++t) {
        float4 nv;
        if (t < N / 256 - 1) nv = arow[(t + 1) * 64 + lane];
#pragma unroll
        for (int s = 0; s < 4; ++s) {
            const float v = (s == 0) ? av.x : (s == 1) ? av.y : (s == 2) ? av.z : av.w;
            const bool hit = v > 0.f;
            const unsigned long long mk = __ballot(hit);
            if (hit) {
                const int pos = base + __popcll(mk & ((1ull << lane) - 1ull));
                if (pos < MAXD) rowidx[pos] = t * 256 + lane * 4 + s;
            }
            base += __popcll(mk);
        }
        av = nv;
    }
    if (lane == 0) cnt[i] = base < MAXD ? base : MAXD;
}

// ---------------------------------------------------------------------------
// K5: edge-list attention. One wave per row, lane == feature.
// All operands (h 4MB, e_dst 64KB, idx 2MB) are L2/L3-resident.
// ---------------------------------------------------------------------------
__global__ __launch_bounds__(256) void k_edge(const float* __restrict__ h,
                                              const float* __restrict__ e_src_p,
                                              const float* __restrict__ e_dst_p,
                                              const float* __restrict__ Dmax,
                                              const int* __restrict__ cnt,
                                              const int* __restrict__ idx,
                                              float* __restrict__ out) {
    const int wave = threadIdx.x >> 6;
    const int lane = threadIdx.x & 63;
    const int i = blockIdx.x * 4 + wave;

    const float4 es4 = *reinterpret_cast<const float4*>(&e_src_p[i * 4]);
    const float es[4] = {es4.x, es4.y, es4.z, es4.w};
    float m[4], lsum[4], acc[4];
#pragma unroll
    for (int hd = 0; hd < 4; ++hd) {
        const float t = es[hd] + Dmax[hd];
        m[hd] = t > 0.f ? t : ALPHA * t;
        lsum[hd] = 0.f;
        acc[hd] = 0.f;
    }

    const int n = cnt[i];
    const int4* jp = reinterpret_cast<const int4*>(idx + i * MAXD);
    int4 jv = jp[0];
    const int n4 = (n + 3) >> 2;
    for (int e4 = 0; e4 < n4; ++e4) {
        const int4 cur = jv;
        const int pf = (e4 + 1 < MAXD / 4) ? e4 + 1 : MAXD / 4 - 1;
        jv = jp[pf];                                    // prefetch next
#pragma unroll
        for (int u = 0; u < 4; ++u) {
            const int e = e4 * 4 + u;
            if (e < n) {
                const int j = (u == 0) ? cur.x : (u == 1) ? cur.y : (u == 2) ? cur.z : cur.w;
                const float4 ed4 = *reinterpret_cast<const float4*>(&e_dst_p[j * 4]);
                const float edv[4] = {ed4.x, ed4.y, ed4.z, ed4.w};
#pragma unroll
                for (int hd = 0; hd < 4; ++hd) {
                    float z = es[hd] + edv[hd];
                    z = z > 0.f ? z : ALPHA * z;
                    const float w = __expf(z - m[hd]);
                    lsum[hd] += w;
                    acc[hd] = fmaf(w, h[j * 256 + hd * 64 + lane], acc[hd]);
                }
            }
        }
    }

#pragma unroll
    for (int hd = 0; hd < 4; ++hd) {
        const float v = acc[hd] / lsum[hd];
        out[i * 256 + hd * 64 + lane] = v > 0.f ? v : __expf(v) - 1.f;
    }
}

// ---------------------------------------------------------------------------
extern "C" void kernel_launch(void* const* d_in, const int* in_sizes, int n_in,
                              void* d_out, int out_size, void* d_ws, size_t ws_size,
                              hipStream_t stream) {
    const float* x   = (const float*)d_in[0];
    const float* adj = (const float*)d_in[1];
    const float* W   = (const float*)d_in[2];
    const float* a   = (const float*)d_in[3];
    float* out = (float*)d_out;

    float* ws      = (float*)d_ws;
    float* ham     = ws;                          // 4*256*64   = 65536
    float* h       = ham + HEADS * IN_F * OUT_F;  // 4096*256   = 1048576
    float* e_src_p = h + N * HEADS * OUT_F;       // 4096*4
    float* e_dst_p = e_src_p + N * HEADS;         // 4096*4
    float* Dmax    = e_dst_p + N * HEADS;         // 4 (+pad)
    int*   csr_cnt = (int*)(Dmax + 16);           // 4096
    int*   csr_idx = csr_cnt + N;                 // 4096*128

    k_build_ham<<<256, 256, 0, stream>>>(W, ham);
    k_hgemm<<<dim3(N / (4 * RPW), HEADS), 256, 0, stream>>>(x, ham, a, h, e_src_p, e_dst_p);
    k_dmax<<<HEADS, 256, 0, stream>>>(e_dst_p, Dmax);
    k_csr<<<N / 4, 256, 0, stream>>>(adj, csr_cnt, csr_idx);
    k_edge<<<N / 4, 256, 0, stream>>>(h, e_src_p, e_dst_p, Dmax, csr_cnt, csr_idx, out);
}

// Round 3
// 67.781 us; speedup vs baseline: 1.2143x; 1.2143x over previous
//
#include <hip/hip_runtime.h>

#define N 4096
#define IN_F 256
#define OUT_F 64
#define HEADS 4
#define ALPHA 0.2f
#define MAXD 128  // max row degree (mean ~21, binomial tail << 128)

// ---------------------------------------------------------------------------
// K1: build hamilton[4][256][64] from W_heads[4][64][64]
// ---------------------------------------------------------------------------
__global__ __launch_bounds__(256) void k_build_ham(const float* __restrict__ W,
                                                   float* __restrict__ ham) {
    int tid = blockIdx.x * 256 + threadIdx.x;          // 0..65535
    int hd = tid >> 14;
    int kk = (tid >> 6) & 255;
    int f  = tid & 63;
    int q = kk >> 6, kr = kk & 63;
    int p = f >> 4,  fr = f & 15;
    const int   comp_t[4][4] = {{0,1,2,3},{1,0,3,2},{2,3,0,1},{3,2,1,0}};
    const float sign_t[4][4] = {{1.f,-1.f,-1.f,-1.f},
                                {1.f, 1.f,-1.f, 1.f},
                                {1.f, 1.f, 1.f,-1.f},
                                {1.f,-1.f, 1.f, 1.f}};
    int   c = comp_t[q][p];
    float s = sign_t[q][p];
    ham[tid] = s * W[(hd * 64 + kr) * 64 + c * 16 + fr];
}

// ---------------------------------------------------------------------------
// K2: transpose x [4096][256] -> xT [256][4096]  (tiled via LDS, +1 pad)
// ---------------------------------------------------------------------------
__global__ __launch_bounds__(256) void k_xT(const float* __restrict__ x,
                                            float* __restrict__ xT) {
    __shared__ float t[64][65];
    const int i0 = blockIdx.x * 64;
    const int k0 = blockIdx.y * 64;
    const int lane = threadIdx.x & 63;
    const int grp  = threadIdx.x >> 6;   // 0..3
#pragma unroll
    for (int e = 0; e < 16; ++e) {
        const int il = grp * 16 + e;
        t[lane][il] = x[(i0 + il) * IN_F + k0 + lane];   // coalesced over k
    }
    __syncthreads();
#pragma unroll
    for (int e = 0; e < 16; ++e) {
        const int kl = grp * 16 + e;
        xT[(size_t)(k0 + kl) * N + i0 + lane] = t[kl][lane];  // coalesced over i
    }
}

// ---------------------------------------------------------------------------
// K3: h[i][hd*64+f] = sum_k x[i][k] * ham[hd][k][f]
// lane == row, 8 features per wave in registers. xT load coalesced + pipelined;
// ham operands wave-uniform -> scalar loads (SMEM pipe, off critical path).
// Fused e_src/e_dst via LDS cross-wave reduction.
// ---------------------------------------------------------------------------
__global__ __launch_bounds__(512) void k_hgemm(const float* __restrict__ xT,
                                               const float* __restrict__ ham,
                                               const float* __restrict__ a,
                                               float* __restrict__ h,
                                               float* __restrict__ e_src_p,
                                               float* __restrict__ e_dst_p) {
    __shared__ float red_p[8][64];
    __shared__ float red_q[8][64];

    const int hd   = blockIdx.y;
    const int lane = threadIdx.x & 63;
    const int wave = threadIdx.x >> 6;                 // 0..7
    const int f0   = __builtin_amdgcn_readfirstlane(wave * 8);
    const int i0   = blockIdx.x * 64;
    const int i    = i0 + lane;

    const float* __restrict__ hamh = ham + hd * (IN_F * OUT_F);

    float acc[8];
#pragma unroll
    for (int e = 0; e < 8; ++e) acc[e] = 0.f;

#pragma unroll 4
    for (int k = 0; k < IN_F; ++k) {
        const float xv = xT[(size_t)k * N + i0 + lane];           // coalesced
        const float4 hv0 = *reinterpret_cast<const float4*>(hamh + k * OUT_F + f0);
        const float4 hv1 = *reinterpret_cast<const float4*>(hamh + k * OUT_F + f0 + 4);
        acc[0] = fmaf(xv, hv0.x, acc[0]);
        acc[1] = fmaf(xv, hv0.y, acc[1]);
        acc[2] = fmaf(xv, hv0.z, acc[2]);
        acc[3] = fmaf(xv, hv0.w, acc[3]);
        acc[4] = fmaf(xv, hv1.x, acc[4]);
        acc[5] = fmaf(xv, hv1.y, acc[5]);
        acc[6] = fmaf(xv, hv1.z, acc[6]);
        acc[7] = fmaf(xv, hv1.w, acc[7]);
    }

    // store h (two float4 per lane)
    float* hp = h + (size_t)i * (HEADS * OUT_F) + hd * OUT_F + f0;
    *reinterpret_cast<float4*>(hp)     = make_float4(acc[0], acc[1], acc[2], acc[3]);
    *reinterpret_cast<float4*>(hp + 4) = make_float4(acc[4], acc[5], acc[6], acc[7]);

    // fused attention-coefficient dot products (uniform a loads)
    float p = 0.f, q = 0.f;
#pragma unroll
    for (int e = 0; e < 8; ++e) {
        p = fmaf(acc[e], a[hd * 128 + f0 + e], p);
        q = fmaf(acc[e], a[hd * 128 + 64 + f0 + e], q);
    }
    red_p[wave][lane] = p;
    red_q[wave][lane] = q;
    __syncthreads();
    if (wave == 0) {
        float s = 0.f;
#pragma unroll
        for (int w = 0; w < 8; ++w) s += red_p[w][lane];
        e_src_p[i * 4 + hd] = s;
    } else if (wave == 1) {
        float s = 0.f;
#pragma unroll
        for (int w = 0; w < 8; ++w) s += red_q[w][lane];
        e_dst_p[i * 4 + hd] = s;
    }
}

// ---------------------------------------------------------------------------
// K4: Dmax[hd] = max_j e_dst[hd][j]  (upper bound for shift-stable softmax)
// ---------------------------------------------------------------------------
__global__ __launch_bounds__(256) void k_dmax(const float* __restrict__ e_dst_p,
                                              float* __restrict__ Dmax) {
    __shared__ float sm[256];
    const int hd = blockIdx.x;
    float m = -3.0e38f;
    for (int j = threadIdx.x; j < N; j += 256)
        m = fmaxf(m, e_dst_p[j * 4 + hd]);
    sm[threadIdx.x] = m;
    __syncthreads();
    for (int s = 128; s > 0; s >>= 1) {
        if (threadIdx.x < s) sm[threadIdx.x] = fmaxf(sm[threadIdx.x], sm[threadIdx.x + s]);
        __syncthreads();
    }
    if (threadIdx.x == 0) Dmax[hd] = sm[0];
}

// ---------------------------------------------------------------------------
// K5: fused masked-softmax attention, one wave per row.
// Phase 1: stream adj row; hit lanes compute exp-weights IN PARALLEL and push
//          (j, w[4]) to a wave-local LDS list; lsum via shuffle reduce.
// Phase 2: lane == feature; edge loop with j-prefetch, h rows L2-resident.
// ---------------------------------------------------------------------------
__global__ __launch_bounds__(256) void k_attn(const float* __restrict__ adj,
                                              const float* __restrict__ h,
                                              const float* __restrict__ e_src_p,
                                              const float* __restrict__ e_dst_p,
                                              const float* __restrict__ Dmax,
                                              float* __restrict__ out) {
    __shared__ int    s_j[4][MAXD];
    __shared__ float4 s_w[4][MAXD];

    const int wave = threadIdx.x >> 6;
    const int lane = threadIdx.x & 63;
    const int i = blockIdx.x * 4 + wave;

    const float4 es4 = *reinterpret_cast<const float4*>(&e_src_p[i * 4]);
    const float es[4] = {es4.x, es4.y, es4.z, es4.w};
    float m[4], lsp[4];
#pragma unroll
    for (int hd = 0; hd < 4; ++hd) {
        const float t = es[hd] + Dmax[hd];
        m[hd] = t > 0.f ? t : ALPHA * t;
        lsp[hd] = 0.f;
    }

    // ---- phase 1: scan + weight computation ----
    const uint4* arow = reinterpret_cast<const uint4*>(adj + (size_t)i * N);
    const unsigned long long lmask_lt = (lane == 63) ? ~0ull >> 1
                                                     : (1ull << lane) - 1ull;
    int base = 0;
    for (int t = 0; t < N / 256; ++t) {
        const uint4 av = arow[t * 64 + lane];
#pragma unroll
        for (int s = 0; s < 4; ++s) {
            const unsigned v = (s == 0) ? av.x : (s == 1) ? av.y : (s == 2) ? av.z : av.w;
            const bool hit = v != 0u;   // adj entries are exactly 0.0f or 1.0f
            const unsigned long long mk = __ballot(hit);
            if (hit) {
                const int pos = base + __popcll(mk & lmask_lt);
                const int j = t * 256 + lane * 4 + s;
                const float4 ed = *reinterpret_cast<const float4*>(&e_dst_p[j * 4]);
                float4 wv;
                float z;
                z = es[0] + ed.x; z = z > 0.f ? z : ALPHA * z; wv.x = __expf(z - m[0]);
                z = es[1] + ed.y; z = z > 0.f ? z : ALPHA * z; wv.y = __expf(z - m[1]);
                z = es[2] + ed.z; z = z > 0.f ? z : ALPHA * z; wv.z = __expf(z - m[2]);
                z = es[3] + ed.w; z = z > 0.f ? z : ALPHA * z; wv.w = __expf(z - m[3]);
                lsp[0] += wv.x; lsp[1] += wv.y; lsp[2] += wv.z; lsp[3] += wv.w;
                if (pos < MAXD) { s_j[wave][pos] = j; s_w[wave][pos] = wv; }
            }
            base += __popcll(mk);
        }
    }

    // wave-wide lsum reduce (all lanes get totals)
#pragma unroll
    for (int off = 32; off > 0; off >>= 1) {
        lsp[0] += __shfl_xor(lsp[0], off);
        lsp[1] += __shfl_xor(lsp[1], off);
        lsp[2] += __shfl_xor(lsp[2], off);
        lsp[3] += __shfl_xor(lsp[3], off);
    }

    // ---- phase 2: edge accumulation, lane == feature ----
    const int cnt = base < MAXD ? base : MAXD;
    float acc[4] = {0.f, 0.f, 0.f, 0.f};
    int j = s_j[wave][0];                      // cnt >= 1 (self-loop)
    for (int e = 0; e < cnt; ++e) {
        const int jn = (e + 1 < cnt) ? s_j[wave][e + 1] : j;   // prefetch index
        const float4 wv = s_w[wave][e];
        const float* hj = h + (size_t)j * (HEADS * OUT_F) + lane;
        acc[0] = fmaf(wv.x, hj[0],   acc[0]);
        acc[1] = fmaf(wv.y, hj[64],  acc[1]);
        acc[2] = fmaf(wv.z, hj[128], acc[2]);
        acc[3] = fmaf(wv.w, hj[192], acc[3]);
        j = jn;
    }

#pragma unroll
    for (int hd = 0; hd < 4; ++hd) {
        const float v = acc[hd] / lsp[hd];
        out[i * 256 + hd * 64 + lane] = v > 0.f ? v : __expf(v) - 1.f;
    }
}

// ---------------------------------------------------------------------------
extern "C" void kernel_launch(void* const* d_in, const int* in_sizes, int n_in,
                              void* d_out, int out_size, void* d_ws, size_t ws_size,
                              hipStream_t stream) {
    const float* x   = (const float*)d_in[0];
    const float* adj = (const float*)d_in[1];
    const float* W   = (const float*)d_in[2];
    const float* a   = (const float*)d_in[3];
    float* out = (float*)d_out;

    float* ws      = (float*)d_ws;
    float* ham     = ws;                          // 4*256*64   = 65536
    float* xT      = ham + HEADS * IN_F * OUT_F;  // 256*4096   = 1048576
    float* h       = xT + IN_F * N;               // 4096*256   = 1048576
    float* e_src_p = h + N * HEADS * OUT_F;       // 4096*4
    float* e_dst_p = e_src_p + N * HEADS;         // 4096*4
    float* Dmax    = e_dst_p + N * HEADS;         // 4 (+pad)

    k_build_ham<<<256, 256, 0, stream>>>(W, ham);
    k_xT<<<dim3(N / 64, IN_F / 64), 256, 0, stream>>>(x, xT);
    k_hgemm<<<dim3(N / 64, HEADS), 512, 0, stream>>>(xT, ham, a, h, e_src_p, e_dst_p);
    k_dmax<<<HEADS, 256, 0, stream>>>(e_dst_p, Dmax);
    k_attn<<<N / 4, 256, 0, stream>>>(adj, h, e_src_p, e_dst_p, Dmax, out);
}

// Round 4
// 47.721 us; speedup vs baseline: 1.7247x; 1.4204x over previous
//
#include <hip/hip_runtime.h>

#define N 4096
#define IN_F 256
#define OUT_F 64
#define HEADS 4
#define ALPHA 0.2f
#define MAXD 128  // max row degree (mean ~21; binomial tail ≪ 128)

typedef __attribute__((ext_vector_type(8))) short short8;
typedef __attribute__((ext_vector_type(4))) float f32x4;

__device__ __forceinline__ unsigned short f2bf(float f) {
    unsigned u = __builtin_bit_cast(unsigned, f);
    u += 0x7fffu + ((u >> 16) & 1u);            // round-to-nearest-even
    return (unsigned short)(u >> 16);
}

// ---------------------------------------------------------------------------
// K1: cast x -> bf16 AND build transposed bf16 hamilton hamT[hd][f][k].
// hamT[hd][f][k] = sign[q][p] * W[hd][kr][comp[q][p]*16+fr],
//   k = q*64+kr, f = p*16+fr   (same math as verified k_build_ham).
// ---------------------------------------------------------------------------
__global__ __launch_bounds__(256) void k_prep(const float* __restrict__ x,
                                              const float* __restrict__ W,
                                              unsigned short* __restrict__ xb,
                                              unsigned short* __restrict__ hamT) {
    const int tid = blockIdx.x * 256 + threadIdx.x;      // 262144 threads
    const float4 xv = *reinterpret_cast<const float4*>(x + (size_t)tid * 4);
    ushort4 o;
    o.x = f2bf(xv.x); o.y = f2bf(xv.y); o.z = f2bf(xv.z); o.w = f2bf(xv.w);
    *reinterpret_cast<ushort4*>(xb + (size_t)tid * 4) = o;

    if (tid < HEADS * OUT_F * IN_F) {                    // 65536
        const int hd = tid >> 14, f = (tid >> 8) & 63, k = tid & 255;
        const int q = k >> 6, kr = k & 63, p = f >> 4, fr = f & 15;
        const int   comp_t[4][4] = {{0,1,2,3},{1,0,3,2},{2,3,0,1},{3,2,1,0}};
        const float sign_t[4][4] = {{1.f,-1.f,-1.f,-1.f},
                                    {1.f, 1.f,-1.f, 1.f},
                                    {1.f, 1.f, 1.f,-1.f},
                                    {1.f,-1.f, 1.f, 1.f}};
        hamT[tid] = f2bf(sign_t[q][p] * W[(hd * 64 + kr) * 64 + comp_t[q][p] * 16 + fr]);
    }
}

// ---------------------------------------------------------------------------
// K2: h = x @ ham via bf16 MFMA (fp32 accum). One wave = 16 rows x 1 head.
// Fused e_src/e_dst dot products (f is lane-local per 16-group in D layout)
// and per-wave e_dst max -> wmax.
// ---------------------------------------------------------------------------
__global__ __launch_bounds__(256) void k_h(const unsigned short* __restrict__ xb,
                                           const unsigned short* __restrict__ hamT,
                                           const float* __restrict__ a,
                                           float* __restrict__ h,
                                           float* __restrict__ e_src_p,
                                           float* __restrict__ e_dst_p,
                                           float* __restrict__ wmax) {
    const int wave = threadIdx.x >> 6, lane = threadIdx.x & 63;
    const int gw = blockIdx.x * 4 + wave;     // 0..1023
    const int rg = gw >> 2, hd = gw & 3;
    const int m0 = rg * 16;
    const int r16 = lane & 15, g = lane >> 4;

    // A fragments: rows m0+r16, k-chunks of 32 (8 bf16 per lane per chunk)
    const unsigned short* xrow = xb + (size_t)(m0 + r16) * IN_F + g * 8;
    short8 af[8];
#pragma unroll
    for (int kk = 0; kk < 8; ++kk)
        af[kk] = *reinterpret_cast<const short8*>(xrow + kk * 32);

    f32x4 acc[4];
#pragma unroll
    for (int t = 0; t < 4; ++t) acc[t] = (f32x4){0.f, 0.f, 0.f, 0.f};

    // B fragments: cols hd*64 + t*16 + r16, contiguous k in hamT
    const unsigned short* hbase = hamT + (size_t)(hd * 64 + r16) * IN_F + g * 8;
#pragma unroll
    for (int kk = 0; kk < 8; ++kk) {
#pragma unroll
        for (int t = 0; t < 4; ++t) {
            const short8 bf = *reinterpret_cast<const short8*>(hbase + t * 16 * IN_F + kk * 32);
            acc[t] = __builtin_amdgcn_mfma_f32_16x16x32_bf16(af[kk], bf, acc[t], 0, 0, 0);
        }
    }

    // D layout: value acc[t][j] is at (row = g*4 + j, col/f = t*16 + r16)
    float p[4] = {0.f, 0.f, 0.f, 0.f}, q[4] = {0.f, 0.f, 0.f, 0.f};
#pragma unroll
    for (int t = 0; t < 4; ++t) {
        const float as = a[hd * 128 + t * 16 + r16];
        const float ad = a[hd * 128 + 64 + t * 16 + r16];
#pragma unroll
        for (int j = 0; j < 4; ++j) {
            const float v = acc[t][j];
            h[(size_t)(m0 + g * 4 + j) * (HEADS * OUT_F) + hd * 64 + t * 16 + r16] = v;
            p[j] = fmaf(v, as, p[j]);
            q[j] = fmaf(v, ad, q[j]);
        }
    }
    // reduce over f (r16) within each 16-lane group
#pragma unroll
    for (int off = 1; off < 16; off <<= 1) {
#pragma unroll
        for (int j = 0; j < 4; ++j) {
            p[j] += __shfl_xor(p[j], off);
            q[j] += __shfl_xor(q[j], off);
        }
    }
    if (r16 == 0) {
#pragma unroll
        for (int j = 0; j < 4; ++j) {
            e_src_p[(m0 + g * 4 + j) * 4 + hd] = p[j];
            e_dst_p[(m0 + g * 4 + j) * 4 + hd] = q[j];
        }
    }
    float qm = fmaxf(fmaxf(q[0], q[1]), fmaxf(q[2], q[3]));
    qm = fmaxf(qm, __shfl_xor(qm, 16));
    qm = fmaxf(qm, __shfl_xor(qm, 32));
    if (lane == 0) wmax[rg * 4 + hd] = qm;
}

// ---------------------------------------------------------------------------
// K3: Dmax[hd] = max over 256 wave partials
// ---------------------------------------------------------------------------
__global__ __launch_bounds__(256) void k_dmax(const float* __restrict__ wmax,
                                              float* __restrict__ Dmax) {
    __shared__ float sm[256];
    const int hd = blockIdx.x;
    sm[threadIdx.x] = wmax[threadIdx.x * 4 + hd];
    __syncthreads();
    for (int s = 128; s > 0; s >>= 1) {
        if (threadIdx.x < s) sm[threadIdx.x] = fmaxf(sm[threadIdx.x], sm[threadIdx.x + s]);
        __syncthreads();
    }
    if (threadIdx.x == 0) Dmax[hd] = sm[0];
}

// ---------------------------------------------------------------------------
// K4: fused masked-softmax attention, one wave per row.
// Phase 1: issue ALL 16 row loads back-to-back (BW saturation), then
//          ballot-compact; hit lanes compute exp-weights in parallel into a
//          wave-local LDS list; lsum via shuffle reduce.
// Phase 2: lane == feature; edge loop, h rows L2-resident.
// ---------------------------------------------------------------------------
__global__ __launch_bounds__(256) void k_attn(const float* __restrict__ adj,
                                              const float* __restrict__ h,
                                              const float* __restrict__ e_src_p,
                                              const float* __restrict__ e_dst_p,
                                              const float* __restrict__ Dmax,
                                              float* __restrict__ out) {
    __shared__ int    s_j[4][MAXD];
    __shared__ float4 s_w[4][MAXD];

    const int wave = threadIdx.x >> 6;
    const int lane = threadIdx.x & 63;
    const int i = blockIdx.x * 4 + wave;

    const float4 es4 = *reinterpret_cast<const float4*>(&e_src_p[i * 4]);
    const float es[4] = {es4.x, es4.y, es4.z, es4.w};
    float m[4], lsp[4];
#pragma unroll
    for (int hd = 0; hd < 4; ++hd) {
        const float t = es[hd] + Dmax[hd];
        m[hd] = t > 0.f ? t : ALPHA * t;
        lsp[hd] = 0.f;
    }

    // ---- phase 1: registers-first scan ----
    const uint4* arow = reinterpret_cast<const uint4*>(adj + (size_t)i * N);
    uint4 av[16];
#pragma unroll
    for (int t = 0; t < 16; ++t) av[t] = arow[t * 64 + lane];

    const unsigned long long lmask_lt = (lane == 63) ? ~0ull >> 1
                                                     : (1ull << lane) - 1ull;
    int base = 0;
#pragma unroll
    for (int t = 0; t < 16; ++t) {
#pragma unroll
        for (int s = 0; s < 4; ++s) {
            const unsigned v = (s == 0) ? av[t].x : (s == 1) ? av[t].y
                             : (s == 2) ? av[t].z : av[t].w;
            const bool hit = v != 0u;            // adj entries are exactly 0/1
            const unsigned long long mk = __ballot(hit);
            if (hit) {
                const int pos = base + __popcll(mk & lmask_lt);
                const int j = t * 256 + lane * 4 + s;
                const float4 ed = *reinterpret_cast<const float4*>(&e_dst_p[j * 4]);
                float4 wv;
                float z;
                z = es[0] + ed.x; z = z > 0.f ? z : ALPHA * z; wv.x = __expf(z - m[0]);
                z = es[1] + ed.y; z = z > 0.f ? z : ALPHA * z; wv.y = __expf(z - m[1]);
                z = es[2] + ed.z; z = z > 0.f ? z : ALPHA * z; wv.z = __expf(z - m[2]);
                z = es[3] + ed.w; z = z > 0.f ? z : ALPHA * z; wv.w = __expf(z - m[3]);
                lsp[0] += wv.x; lsp[1] += wv.y; lsp[2] += wv.z; lsp[3] += wv.w;
                if (pos < MAXD) { s_j[wave][pos] = j; s_w[wave][pos] = wv; }
            }
            base += __popcll(mk);
        }
    }

#pragma unroll
    for (int off = 32; off > 0; off >>= 1) {
        lsp[0] += __shfl_xor(lsp[0], off);
        lsp[1] += __shfl_xor(lsp[1], off);
        lsp[2] += __shfl_xor(lsp[2], off);
        lsp[3] += __shfl_xor(lsp[3], off);
    }

    // ---- phase 2: edge accumulation, lane == feature ----
    const int cnt = base < MAXD ? base : MAXD;
    float acc[4] = {0.f, 0.f, 0.f, 0.f};
    int j = s_j[wave][0];                        // cnt >= 1 (self-loop)
    for (int e = 0; e < cnt; ++e) {
        const int jn = (e + 1 < cnt) ? s_j[wave][e + 1] : j;
        const float4 wv = s_w[wave][e];
        const float* hj = h + (size_t)j * (HEADS * OUT_F) + lane;
        acc[0] = fmaf(wv.x, hj[0],   acc[0]);
        acc[1] = fmaf(wv.y, hj[64],  acc[1]);
        acc[2] = fmaf(wv.z, hj[128], acc[2]);
        acc[3] = fmaf(wv.w, hj[192], acc[3]);
        j = jn;
    }

#pragma unroll
    for (int hd = 0; hd < 4; ++hd) {
        const float v = acc[hd] / lsp[hd];
        out[i * 256 + hd * 64 + lane] = v > 0.f ? v : __expf(v) - 1.f;
    }
}

// ---------------------------------------------------------------------------
extern "C" void kernel_launch(void* const* d_in, const int* in_sizes, int n_in,
                              void* d_out, int out_size, void* d_ws, size_t ws_size,
                              hipStream_t stream) {
    const float* x   = (const float*)d_in[0];
    const float* adj = (const float*)d_in[1];
    const float* W   = (const float*)d_in[2];
    const float* a   = (const float*)d_in[3];
    float* out = (float*)d_out;

    float* ws      = (float*)d_ws;
    float* h       = ws;                       // 4096*256 = 1048576 floats
    float* e_src_p = h + (size_t)N * 256;      // 16384
    float* e_dst_p = e_src_p + N * 4;          // 16384
    float* wmax    = e_dst_p + N * 4;          // 1024
    float* Dmax    = wmax + 1024;              // 4 (+12 pad)
    unsigned short* xb   = (unsigned short*)(Dmax + 16);  // 1048576 bf16
    unsigned short* hamT = xb + (size_t)N * IN_F;         // 65536 bf16

    k_prep<<<1024, 256, 0, stream>>>(x, W, xb, hamT);
    k_h<<<256, 256, 0, stream>>>(xb, hamT, a, h, e_src_p, e_dst_p, wmax);
    k_dmax<<<4, 256, 0, stream>>>(wmax, Dmax);
    k_attn<<<N / 4, 256, 0, stream>>>(adj, h, e_src_p, e_dst_p, Dmax, out);
}

// Round 5
// 43.891 us; speedup vs baseline: 1.8752x; 1.0873x over previous
//
#include <hip/hip_runtime.h>

#define N 4096
#define IN_F 256
#define OUT_F 64
#define HEADS 4
#define ALPHA 0.2f
#define SEG 64    // max hits per quarter-row segment (mean ~5.4; huge margin)

typedef __attribute__((ext_vector_type(8))) short short8;
typedef __attribute__((ext_vector_type(4))) float f32x4;

__device__ __forceinline__ unsigned short f2bf(float f) {
    unsigned u = __builtin_bit_cast(unsigned, f);
    u += 0x7fffu + ((u >> 16) & 1u);            // round-to-nearest-even
    return (unsigned short)(u >> 16);
}

// ---------------------------------------------------------------------------
// K1: cast x -> bf16 AND build transposed bf16 hamilton hamT[hd][f][k].
// ---------------------------------------------------------------------------
__global__ __launch_bounds__(256) void k_prep(const float* __restrict__ x,
                                              const float* __restrict__ W,
                                              unsigned short* __restrict__ xb,
                                              unsigned short* __restrict__ hamT) {
    const int tid = blockIdx.x * 256 + threadIdx.x;      // 262144 threads
    const float4 xv = *reinterpret_cast<const float4*>(x + (size_t)tid * 4);
    ushort4 o;
    o.x = f2bf(xv.x); o.y = f2bf(xv.y); o.z = f2bf(xv.z); o.w = f2bf(xv.w);
    *reinterpret_cast<ushort4*>(xb + (size_t)tid * 4) = o;

    if (tid < HEADS * OUT_F * IN_F) {                    // 65536
        const int hd = tid >> 14, f = (tid >> 8) & 63, k = tid & 255;
        const int q = k >> 6, kr = k & 63, p = f >> 4, fr = f & 15;
        const int   comp_t[4][4] = {{0,1,2,3},{1,0,3,2},{2,3,0,1},{3,2,1,0}};
        const float sign_t[4][4] = {{1.f,-1.f,-1.f,-1.f},
                                    {1.f, 1.f,-1.f, 1.f},
                                    {1.f, 1.f, 1.f,-1.f},
                                    {1.f,-1.f, 1.f, 1.f}};
        hamT[tid] = f2bf(sign_t[q][p] * W[(hd * 64 + kr) * 64 + comp_t[q][p] * 16 + fr]);
    }
}

// ---------------------------------------------------------------------------
// K2: h = x @ ham via bf16 MFMA (fp32 accum). One wave = 16 rows x 1 head.
// Fused e_src/e_dst dots + per-wave e_dst max.
// ---------------------------------------------------------------------------
__global__ __launch_bounds__(256) void k_h(const unsigned short* __restrict__ xb,
                                           const unsigned short* __restrict__ hamT,
                                           const float* __restrict__ a,
                                           float* __restrict__ h,
                                           float* __restrict__ e_src_p,
                                           float* __restrict__ e_dst_p,
                                           float* __restrict__ wmax) {
    const int wave = threadIdx.x >> 6, lane = threadIdx.x & 63;
    const int gw = blockIdx.x * 4 + wave;     // 0..1023
    const int rg = gw >> 2, hd = gw & 3;
    const int m0 = rg * 16;
    const int r16 = lane & 15, g = lane >> 4;

    const unsigned short* xrow = xb + (size_t)(m0 + r16) * IN_F + g * 8;
    short8 af[8];
#pragma unroll
    for (int kk = 0; kk < 8; ++kk)
        af[kk] = *reinterpret_cast<const short8*>(xrow + kk * 32);

    f32x4 acc[4];
#pragma unroll
    for (int t = 0; t < 4; ++t) acc[t] = (f32x4){0.f, 0.f, 0.f, 0.f};

    const unsigned short* hbase = hamT + (size_t)(hd * 64 + r16) * IN_F + g * 8;
#pragma unroll
    for (int kk = 0; kk < 8; ++kk) {
#pragma unroll
        for (int t = 0; t < 4; ++t) {
            const short8 bf = *reinterpret_cast<const short8*>(hbase + t * 16 * IN_F + kk * 32);
            acc[t] = __builtin_amdgcn_mfma_f32_16x16x32_bf16(af[kk], bf, acc[t], 0, 0, 0);
        }
    }

    // D layout: acc[t][j] at (row = g*4 + j, col f = t*16 + r16)
    float p[4] = {0.f, 0.f, 0.f, 0.f}, q[4] = {0.f, 0.f, 0.f, 0.f};
#pragma unroll
    for (int t = 0; t < 4; ++t) {
        const float as = a[hd * 128 + t * 16 + r16];
        const float ad = a[hd * 128 + 64 + t * 16 + r16];
#pragma unroll
        for (int j = 0; j < 4; ++j) {
            const float v = acc[t][j];
            h[(size_t)(m0 + g * 4 + j) * (HEADS * OUT_F) + hd * 64 + t * 16 + r16] = v;
            p[j] = fmaf(v, as, p[j]);
            q[j] = fmaf(v, ad, q[j]);
        }
    }
#pragma unroll
    for (int off = 1; off < 16; off <<= 1) {
#pragma unroll
        for (int j = 0; j < 4; ++j) {
            p[j] += __shfl_xor(p[j], off);
            q[j] += __shfl_xor(q[j], off);
        }
    }
    if (r16 == 0) {
#pragma unroll
        for (int j = 0; j < 4; ++j) {
            e_src_p[(m0 + g * 4 + j) * 4 + hd] = p[j];
            e_dst_p[(m0 + g * 4 + j) * 4 + hd] = q[j];
        }
    }
    float qm = fmaxf(fmaxf(q[0], q[1]), fmaxf(q[2], q[3]));
    qm = fmaxf(qm, __shfl_xor(qm, 16));
    qm = fmaxf(qm, __shfl_xor(qm, 32));
    if (lane == 0) wmax[rg * 4 + hd] = qm;
}

// ---------------------------------------------------------------------------
// K3: Dmax[hd] = max over 256 wave partials
// ---------------------------------------------------------------------------
__global__ __launch_bounds__(256) void k_dmax(const float* __restrict__ wmax,
                                              float* __restrict__ Dmax) {
    __shared__ float sm[256];
    const int hd = blockIdx.x;
    sm[threadIdx.x] = wmax[threadIdx.x * 4 + hd];
    __syncthreads();
    for (int s = 128; s > 0; s >>= 1) {
        if (threadIdx.x < s) sm[threadIdx.x] = fmaxf(sm[threadIdx.x], sm[threadIdx.x + s]);
        __syncthreads();
    }
    if (threadIdx.x == 0) Dmax[hd] = sm[0];
}

// ---------------------------------------------------------------------------
// K4: fused masked-softmax attention. ONE BLOCK PER ROW.
// Phase 1: each wave ballot-compacts its quarter row (16 ballots) -> per-wave
//          list; lists merged into one contiguous LDS list (deterministic
//          segment-major order).
// Phase 2: 256 threads = (head, feature); edge loop unrolled x4 with batched
//          j / e_dst / h loads (4-deep memory pipelining). One exp per edge
//          per thread; lsum identical within a head group.
// ---------------------------------------------------------------------------
__global__ __launch_bounds__(256) void k_attn(const float* __restrict__ adj,
                                              const float* __restrict__ h,
                                              const float* __restrict__ e_src_p,
                                              const float* __restrict__ e_dst_p,
                                              const float* __restrict__ Dmax,
                                              float* __restrict__ out) {
    __shared__ int s_seg[4][SEG];
    __shared__ int s_cnt[4];
    __shared__ int s_all[4 * SEG];

    const int wave = threadIdx.x >> 6;
    const int lane = threadIdx.x & 63;
    const int i = blockIdx.x;

    // ---- phase 1: per-wave quarter-row compaction ----
    const uint4* arow = reinterpret_cast<const uint4*>(adj + (size_t)i * N) + wave * 256;
    uint4 av[4];
#pragma unroll
    for (int c = 0; c < 4; ++c) av[c] = arow[c * 64 + lane];

    const unsigned long long lmask_lt = (lane == 63) ? ~0ull >> 1
                                                     : (1ull << lane) - 1ull;
    int base = 0;
#pragma unroll
    for (int c = 0; c < 4; ++c) {
#pragma unroll
        for (int s = 0; s < 4; ++s) {
            const unsigned v = (s == 0) ? av[c].x : (s == 1) ? av[c].y
                             : (s == 2) ? av[c].z : av[c].w;
            const bool hit = v != 0u;            // adj entries are exactly 0/1
            const unsigned long long mk = __ballot(hit);
            if (hit) {
                const int pos = base + __popcll(mk & lmask_lt);
                if (pos < SEG)
                    s_seg[wave][pos] = wave * 1024 + c * 256 + lane * 4 + s;
            }
            base += __popcll(mk);
        }
    }
    if (lane == 0) s_cnt[wave] = base < SEG ? base : SEG;
    __syncthreads();

    // merge segments into one contiguous list (deterministic order)
    const int c0 = s_cnt[0], c1 = s_cnt[1], c2 = s_cnt[2], c3 = s_cnt[3];
    const int wbase = (wave > 0 ? c0 : 0) + (wave > 1 ? c1 : 0) + (wave > 2 ? c2 : 0);
    const int wcnt = s_cnt[wave];
    if (lane < wcnt) s_all[wbase + lane] = s_seg[wave][lane];
    __syncthreads();
    const int cnt = c0 + c1 + c2 + c3;

    // ---- phase 2: thread = (head, feature) ----
    const int hd = wave;
    const float es = e_src_p[i * 4 + hd];
    float mh = es + Dmax[hd];
    mh = mh > 0.f ? mh : ALPHA * mh;

    float lsum = 0.f, acc = 0.f;
    int e = 0;
    for (; e + 4 <= cnt; e += 4) {
        const int j0 = s_all[e], j1 = s_all[e + 1], j2 = s_all[e + 2], j3 = s_all[e + 3];
        const float d0 = e_dst_p[j0 * 4 + hd];
        const float d1 = e_dst_p[j1 * 4 + hd];
        const float d2 = e_dst_p[j2 * 4 + hd];
        const float d3 = e_dst_p[j3 * 4 + hd];
        const float h0 = h[(size_t)j0 * 256 + threadIdx.x];
        const float h1 = h[(size_t)j1 * 256 + threadIdx.x];
        const float h2 = h[(size_t)j2 * 256 + threadIdx.x];
        const float h3 = h[(size_t)j3 * 256 + threadIdx.x];
        float z0 = es + d0; z0 = z0 > 0.f ? z0 : ALPHA * z0;
        float z1 = es + d1; z1 = z1 > 0.f ? z1 : ALPHA * z1;
        float z2 = es + d2; z2 = z2 > 0.f ? z2 : ALPHA * z2;
        float z3 = es + d3; z3 = z3 > 0.f ? z3 : ALPHA * z3;
        const float w0 = __expf(z0 - mh);
        const float w1 = __expf(z1 - mh);
        const float w2 = __expf(z2 - mh);
        const float w3 = __expf(z3 - mh);
        lsum += w0 + w1 + w2 + w3;
        acc = fmaf(w0, h0, acc);
        acc = fmaf(w1, h1, acc);
        acc = fmaf(w2, h2, acc);
        acc = fmaf(w3, h3, acc);
    }
    for (; e < cnt; ++e) {
        const int j = s_all[e];
        const float d = e_dst_p[j * 4 + hd];
        const float hv = h[(size_t)j * 256 + threadIdx.x];
        float z = es + d; z = z > 0.f ? z : ALPHA * z;
        const float w = __expf(z - mh);
        lsum += w;
        acc = fmaf(w, hv, acc);
    }

    const float v = acc / lsum;
    out[(size_t)i * 256 + threadIdx.x] = v > 0.f ? v : __expf(v) - 1.f;
}

// ---------------------------------------------------------------------------
extern "C" void kernel_launch(void* const* d_in, const int* in_sizes, int n_in,
                              void* d_out, int out_size, void* d_ws, size_t ws_size,
                              hipStream_t stream) {
    const float* x   = (const float*)d_in[0];
    const float* adj = (const float*)d_in[1];
    const float* W   = (const float*)d_in[2];
    const float* a   = (const float*)d_in[3];
    float* out = (float*)d_out;

    float* ws      = (float*)d_ws;
    float* h       = ws;                       // 4096*256 = 1048576 floats
    float* e_src_p = h + (size_t)N * 256;      // 16384
    float* e_dst_p = e_src_p + N * 4;          // 16384
    float* wmax    = e_dst_p + N * 4;          // 1024
    float* Dmax    = wmax + 1024;              // 4 (+12 pad)
    unsigned short* xb   = (unsigned short*)(Dmax + 16);  // 1048576 bf16
    unsigned short* hamT = xb + (size_t)N * IN_F;         // 65536 bf16

    k_prep<<<1024, 256, 0, stream>>>(x, W, xb, hamT);
    k_h<<<256, 256, 0, stream>>>(xb, hamT, a, h, e_src_p, e_dst_p, wmax);
    k_dmax<<<4, 256, 0, stream>>>(wmax, Dmax);
    k_attn<<<N, 256, 0, stream>>>(adj, h, e_src_p, e_dst_p, Dmax, out);
}

// Round 6
// 42.400 us; speedup vs baseline: 1.9411x; 1.0351x over previous
//
#include <hip/hip_runtime.h>

#define N 4096
#define IN_F 256
#define OUT_F 64
#define HEADS 4
#define ALPHA 0.2f
#define SEG 64    // max hits per quarter-row segment (mean ~5.1; >25 sigma margin)

typedef __attribute__((ext_vector_type(8))) short short8;
typedef __attribute__((ext_vector_type(4))) float f32x4;

__device__ __forceinline__ unsigned short f2bf(float f) {
    unsigned u = __builtin_bit_cast(unsigned, f);
    u += 0x7fffu + ((u >> 16) & 1u);            // round-to-nearest-even
    return (unsigned short)(u >> 16);
}

// ---------------------------------------------------------------------------
// K1: cast x -> bf16 AND build transposed bf16 hamilton hamT[hd][f][k].
// ---------------------------------------------------------------------------
__global__ __launch_bounds__(256) void k_prep(const float* __restrict__ x,
                                              const float* __restrict__ W,
                                              unsigned short* __restrict__ xb,
                                              unsigned short* __restrict__ hamT) {
    const int tid = blockIdx.x * 256 + threadIdx.x;      // 262144 threads
    const float4 xv = *reinterpret_cast<const float4*>(x + (size_t)tid * 4);
    ushort4 o;
    o.x = f2bf(xv.x); o.y = f2bf(xv.y); o.z = f2bf(xv.z); o.w = f2bf(xv.w);
    *reinterpret_cast<ushort4*>(xb + (size_t)tid * 4) = o;

    if (tid < HEADS * OUT_F * IN_F) {                    // 65536
        const int hd = tid >> 14, f = (tid >> 8) & 63, k = tid & 255;
        const int q = k >> 6, kr = k & 63, p = f >> 4, fr = f & 15;
        const int   comp_t[4][4] = {{0,1,2,3},{1,0,3,2},{2,3,0,1},{3,2,1,0}};
        const float sign_t[4][4] = {{1.f,-1.f,-1.f,-1.f},
                                    {1.f, 1.f,-1.f, 1.f},
                                    {1.f, 1.f, 1.f,-1.f},
                                    {1.f,-1.f, 1.f, 1.f}};
        hamT[tid] = f2bf(sign_t[q][p] * W[(hd * 64 + kr) * 64 + comp_t[q][p] * 16 + fr]);
    }
}

// ---------------------------------------------------------------------------
// K2: h = x @ ham via bf16 MFMA. One wave = 16 rows x HALF a head (32 cols).
// 2048 waves (512 blocks) -> 2 waves/SIMD for latency hiding.
// e_src/e_dst written as per-half partials esp/edp[row][hd][cf] (deterministic).
// ---------------------------------------------------------------------------
__global__ __launch_bounds__(256) void k_h(const unsigned short* __restrict__ xb,
                                           const unsigned short* __restrict__ hamT,
                                           const float* __restrict__ a,
                                           float* __restrict__ h,
                                           float* __restrict__ esp,
                                           float* __restrict__ edp) {
    const int wave = threadIdx.x >> 6, lane = threadIdx.x & 63;
    const int gw = blockIdx.x * 4 + wave;     // 0..2047
    const int rg = gw >> 3;                   // 0..255  (16-row group)
    const int hd = (gw >> 1) & 3;
    const int cf = gw & 1;                    // column half
    const int m0 = rg * 16;
    const int r16 = lane & 15, g = lane >> 4;

    const unsigned short* xrow = xb + (size_t)(m0 + r16) * IN_F + g * 8;
    short8 af[8];
#pragma unroll
    for (int kk = 0; kk < 8; ++kk)
        af[kk] = *reinterpret_cast<const short8*>(xrow + kk * 32);

    f32x4 acc[2];
#pragma unroll
    for (int t = 0; t < 2; ++t) acc[t] = (f32x4){0.f, 0.f, 0.f, 0.f};

    const unsigned short* hbase = hamT + (size_t)(hd * 64 + cf * 32 + r16) * IN_F + g * 8;
#pragma unroll
    for (int kk = 0; kk < 8; ++kk) {
#pragma unroll
        for (int t = 0; t < 2; ++t) {
            const short8 bf = *reinterpret_cast<const short8*>(hbase + t * 16 * IN_F + kk * 32);
            acc[t] = __builtin_amdgcn_mfma_f32_16x16x32_bf16(af[kk], bf, acc[t], 0, 0, 0);
        }
    }

    // D layout: acc[t][j] at (row = m0 + g*4 + j, col f = cf*32 + t*16 + r16)
    float p[4] = {0.f, 0.f, 0.f, 0.f}, q[4] = {0.f, 0.f, 0.f, 0.f};
#pragma unroll
    for (int t = 0; t < 2; ++t) {
        const int fcol = cf * 32 + t * 16 + r16;
        const float as = a[hd * 128 + fcol];
        const float ad = a[hd * 128 + 64 + fcol];
#pragma unroll
        for (int j = 0; j < 4; ++j) {
            const float v = acc[t][j];
            h[(size_t)(m0 + g * 4 + j) * (HEADS * OUT_F) + hd * 64 + fcol] = v;
            p[j] = fmaf(v, as, p[j]);
            q[j] = fmaf(v, ad, q[j]);
        }
    }
#pragma unroll
    for (int off = 1; off < 16; off <<= 1) {
#pragma unroll
        for (int j = 0; j < 4; ++j) {
            p[j] += __shfl_xor(p[j], off);
            q[j] += __shfl_xor(q[j], off);
        }
    }
    if (r16 == 0) {
#pragma unroll
        for (int j = 0; j < 4; ++j) {
            const int row = m0 + g * 4 + j;
            esp[row * 8 + hd * 2 + cf] = p[j];
            edp[row * 8 + hd * 2 + cf] = q[j];
        }
    }
}

// ---------------------------------------------------------------------------
// K3: fused masked-softmax attention. ONE BLOCK PER ROW. No global Dmax.
// Phase 1: each wave ballot-compacts its quarter row -> merged LDS edge list.
// Phase 1.5: wave == head; lanes stride the edge list, compute z = lrelu(es+ed),
//            cache z in LDS, wave-reduce EXACT per-row masked max.
// Phase 2: thread = (head, feature); unroll-4 pipelined h loads; exp from
//          cached z; ELU epilogue.
// ---------------------------------------------------------------------------
__global__ __launch_bounds__(256) void k_attn(const float* __restrict__ adj,
                                              const float* __restrict__ h,
                                              const float* __restrict__ esp,
                                              const float* __restrict__ edp,
                                              float* __restrict__ out) {
    __shared__ int   s_seg[4][SEG];
    __shared__ int   s_cnt[4];
    __shared__ int   s_all[4 * SEG];
    __shared__ float s_z[4][4 * SEG];

    const int wave = threadIdx.x >> 6;
    const int lane = threadIdx.x & 63;
    const int i = blockIdx.x;

    // ---- phase 1: per-wave quarter-row compaction ----
    const uint4* arow = reinterpret_cast<const uint4*>(adj + (size_t)i * N) + wave * 256;
    uint4 av[4];
#pragma unroll
    for (int c = 0; c < 4; ++c) av[c] = arow[c * 64 + lane];

    const unsigned long long lmask_lt = (lane == 63) ? ~0ull >> 1
                                                     : (1ull << lane) - 1ull;
    int base = 0;
#pragma unroll
    for (int c = 0; c < 4; ++c) {
#pragma unroll
        for (int s = 0; s < 4; ++s) {
            const unsigned v = (s == 0) ? av[c].x : (s == 1) ? av[c].y
                             : (s == 2) ? av[c].z : av[c].w;
            const bool hit = v != 0u;            // adj entries are exactly 0/1
            const unsigned long long mk = __ballot(hit);
            if (hit) {
                const int pos = base + __popcll(mk & lmask_lt);
                if (pos < SEG)
                    s_seg[wave][pos] = wave * 1024 + c * 256 + lane * 4 + s;
            }
            base += __popcll(mk);
        }
    }
    if (lane == 0) s_cnt[wave] = base < SEG ? base : SEG;
    __syncthreads();

    // merge segments into one contiguous list (deterministic order)
    const int c0 = s_cnt[0], c1 = s_cnt[1], c2 = s_cnt[2], c3 = s_cnt[3];
    const int wbase = (wave > 0 ? c0 : 0) + (wave > 1 ? c1 : 0) + (wave > 2 ? c2 : 0);
    const int wcnt = s_cnt[wave];
    if (lane < wcnt) s_all[wbase + lane] = s_seg[wave][lane];
    __syncthreads();
    const int cnt = c0 + c1 + c2 + c3;

    // ---- phase 1.5: exact per-row masked max (wave == head) ----
    const int hd = wave;
    const float es = esp[i * 8 + hd * 2] + esp[i * 8 + hd * 2 + 1];
    float mh = -3.0e38f;
    for (int e = lane; e < cnt; e += 64) {
        const int j = s_all[e];
        const float ed = edp[j * 8 + hd * 2] + edp[j * 8 + hd * 2 + 1];
        float z = es + ed;
        z = z > 0.f ? z : ALPHA * z;
        s_z[hd][e] = z;
        mh = fmaxf(mh, z);
    }
#pragma unroll
    for (int off = 32; off > 0; off >>= 1) mh = fmaxf(mh, __shfl_xor(mh, off));

    // ---- phase 2: thread = (head, feature) ----
    float lsum = 0.f, acc = 0.f;
    int e = 0;
    for (; e + 4 <= cnt; e += 4) {
        const int j0 = s_all[e], j1 = s_all[e + 1], j2 = s_all[e + 2], j3 = s_all[e + 3];
        const float h0 = h[(size_t)j0 * 256 + threadIdx.x];
        const float h1 = h[(size_t)j1 * 256 + threadIdx.x];
        const float h2 = h[(size_t)j2 * 256 + threadIdx.x];
        const float h3 = h[(size_t)j3 * 256 + threadIdx.x];
        const float w0 = __expf(s_z[hd][e]     - mh);
        const float w1 = __expf(s_z[hd][e + 1] - mh);
        const float w2 = __expf(s_z[hd][e + 2] - mh);
        const float w3 = __expf(s_z[hd][e + 3] - mh);
        lsum += w0 + w1 + w2 + w3;
        acc = fmaf(w0, h0, acc);
        acc = fmaf(w1, h1, acc);
        acc = fmaf(w2, h2, acc);
        acc = fmaf(w3, h3, acc);
    }
    for (; e < cnt; ++e) {
        const int j = s_all[e];
        const float hv = h[(size_t)j * 256 + threadIdx.x];
        const float w = __expf(s_z[hd][e] - mh);
        lsum += w;
        acc = fmaf(w, hv, acc);
    }

    const float v = acc / lsum;
    out[(size_t)i * 256 + threadIdx.x] = v > 0.f ? v : __expf(v) - 1.f;
}

// ---------------------------------------------------------------------------
extern "C" void kernel_launch(void* const* d_in, const int* in_sizes, int n_in,
                              void* d_out, int out_size, void* d_ws, size_t ws_size,
                              hipStream_t stream) {
    const float* x   = (const float*)d_in[0];
    const float* adj = (const float*)d_in[1];
    const float* W   = (const float*)d_in[2];
    const float* a   = (const float*)d_in[3];
    float* out = (float*)d_out;

    float* ws   = (float*)d_ws;
    float* h    = ws;                          // 4096*256 = 1048576 floats
    float* esp  = h + (size_t)N * 256;         // 4096*8 = 32768
    float* edp  = esp + N * 8;                 // 32768
    unsigned short* xb   = (unsigned short*)(edp + N * 8);  // 1048576 bf16
    unsigned short* hamT = xb + (size_t)N * IN_F;           // 65536 bf16

    k_prep<<<1024, 256, 0, stream>>>(x, W, xb, hamT);
    k_h<<<512, 256, 0, stream>>>(xb, hamT, a, h, esp, edp);
    k_attn<<<N, 256, 0, stream>>>(adj, h, esp, edp, out);
}